// Round 1
// baseline (119.468 us; speedup 1.0000x reference)
//
#include <hip/hip_runtime.h>
#include <hip/hip_bf16.h>
#include <stdint.h>

#define DD 256
#define NB 16
#define NN 1024
#define MTOT (NB * NN)  // 16384

typedef __attribute__((ext_vector_type(8))) short short8;
typedef __attribute__((ext_vector_type(4))) float f32x4;

__device__ __forceinline__ ushort f2b(float f) {
  uint32_t u = __float_as_uint(f);
  return (ushort)((u + 0x7fffu + ((u >> 16) & 1u)) >> 16);
}

// C[m][e] = sum_k A[m][k] * W[e][k] + bias[e];  M=16384, K=E=256
// A_F32: A is fp32 (feature), else bf16 (h). WRITE_T: also write C^T per batch.
template <bool A_F32, bool WRITE_T>
__global__ __launch_bounds__(256, 1) void gemm_hqk(
    const void* __restrict__ Aptr, const float* __restrict__ W,
    const float* __restrict__ bias, ushort* __restrict__ C,
    ushort* __restrict__ CT) {
  __shared__ ushort Wl[256 * 256];  // 128 KB, bf16, XOR-swizzled
  const int tid = threadIdx.x;

  // Stage W (fp32 -> bf16) into LDS. 16384 float4 chunks / 256 threads.
  for (int i = 0; i < 64; ++i) {
    int idx4 = i * 256 + tid;
    int row = idx4 >> 6;
    int col0 = (idx4 & 63) << 2;
    float4 v = ((const float4*)W)[idx4];
    ushort4 b4;
    b4.x = f2b(v.x); b4.y = f2b(v.y); b4.z = f2b(v.z); b4.w = f2b(v.w);
    int byte = (row * 512 + col0 * 2) ^ ((row & 7) << 4);
    *(ushort4*)((char*)Wl + byte) = b4;
  }
  __syncthreads();

  const int w = tid >> 6, lane = tid & 63, l15 = lane & 15, hi = lane >> 4;
  const int m0 = blockIdx.x * 64 + w * 16;
  const int arow = m0 + l15;

  f32x4 acc[16] = {};

#pragma unroll
  for (int kk = 0; kk < 8; ++kk) {
    const int k0 = kk * 32 + hi * 8;
    short8 a;
    if constexpr (A_F32) {
      const float4* ap = (const float4*)((const float*)Aptr + arow * 256 + k0);
      float4 x = ap[0], y = ap[1];
      a[0] = (short)f2b(x.x); a[1] = (short)f2b(x.y);
      a[2] = (short)f2b(x.z); a[3] = (short)f2b(x.w);
      a[4] = (short)f2b(y.x); a[5] = (short)f2b(y.y);
      a[6] = (short)f2b(y.z); a[7] = (short)f2b(y.w);
    } else {
      a = *(const short8*)((const ushort*)Aptr + arow * 256 + k0);
    }
#pragma unroll
    for (int et = 0; et < 16; ++et) {
      int er = et * 16 + l15;
      short8 bf = *(const short8*)((const char*)Wl +
                                   ((er * 512 + k0 * 2) ^ ((er & 7) << 4)));
      acc[et] = __builtin_amdgcn_mfma_f32_16x16x32_bf16(a, bf, acc[et], 0, 0, 0);
    }
  }

  ushort hvals[16][4];
#pragma unroll
  for (int et = 0; et < 16; ++et) {
    int e = et * 16 + l15;
    float bv = bias[e];
#pragma unroll
    for (int r = 0; r < 4; ++r) {
      ushort hb = f2b(acc[et][r] + bv);
      hvals[et][r] = hb;
      C[(m0 + hi * 4 + r) * 256 + e] = hb;
    }
  }

  if constexpr (WRITE_T) {
    __syncthreads();  // done reading Wl; reuse as transpose buffer [256][64]
    ushort* Tl = Wl;
    const int mloc = w * 16 + hi * 4;
#pragma unroll
    for (int et = 0; et < 16; ++et)
#pragma unroll
      for (int r = 0; r < 4; ++r)
        Tl[(et * 16 + l15) * 64 + mloc + r] = hvals[et][r];
    __syncthreads();
    const int bidx = blockIdx.x >> 4;
    const int n0 = (blockIdx.x & 15) * 64;
    ushort* dst = CT + bidx * (256 * 1024) + tid * 1024 + n0;
    const uint4* src = (const uint4*)(Tl + tid * 64);
#pragma unroll
    for (int j = 0; j < 8; ++j) ((uint4*)dst)[j] = src[j];
  }
}

// Fused flash-style attention: e=leaky(qk^T/16), mask, softmax, out=relu(a@h)
__global__ __launch_bounds__(256, 1) void attn(
    const ushort* __restrict__ Q, const ushort* __restrict__ Kb,
    const ushort* __restrict__ HT, const int* __restrict__ graph,
    float* __restrict__ out) {
  __shared__ ushort Kt[64 * 256];     // 32 KB swizzled
  __shared__ ushort Ht[256 * 64];     // 32 KB swizzled
  __shared__ ushort Pl[4 * 16 * 64];  // 8 KB, per-wave P staging

  const int tid = threadIdx.x;
  const int w = tid >> 6, lane = tid & 63, l15 = lane & 15, hi = lane >> 4;
  const int b = blockIdx.x >> 4;
  const int q0 = (blockIdx.x & 15) * 64;
  const int qrow_a = q0 + w * 16 + l15;    // A-frag row (this lane)
  const int qrow_c = q0 + w * 16 + hi * 4; // C-layout row base (+reg)

  // Hoist Q fragments (16 rows x 256) into registers
  short8 qf[8];
#pragma unroll
  for (int kk = 0; kk < 8; ++kk)
    qf[kk] = *(const short8*)(Q + (b * 1024 + qrow_a) * 256 + kk * 32 + hi * 8);

  float mR[4] = {-1e9f, -1e9f, -1e9f, -1e9f};
  float lR[4] = {0.f, 0.f, 0.f, 0.f};
  f32x4 o[16] = {};

  for (int t = 0; t < 16; ++t) {
    __syncthreads();
    // Stage K tile [64][256] bf16
#pragma unroll
    for (int i = 0; i < 8; ++i) {
      int c = i * 256 + tid;
      int krow = c >> 5, col0 = (c & 31) << 3;
      uint4 v = *(const uint4*)(Kb + (b * 1024 + t * 64 + krow) * 256 + col0);
      *(uint4*)((char*)Kt + ((krow * 512 + col0 * 2) ^ ((krow & 7) << 4))) = v;
    }
    // Stage H^T tile [256][64] bf16
#pragma unroll
    for (int i = 0; i < 8; ++i) {
      int c = i * 256 + tid;
      int drow = c >> 3, col0 = (c & 7) << 3;
      uint4 v = *(const uint4*)(HT + b * (256 * 1024) + drow * 1024 + t * 64 + col0);
      *(uint4*)((char*)Ht + ((drow * 128 + col0 * 2) ^ ((drow & 7) << 4))) = v;
    }
    __syncthreads();

    // S = q @ k^T for this wave's 16 rows x 64 keys
    f32x4 s[4] = {};
#pragma unroll
    for (int kk = 0; kk < 8; ++kk) {
#pragma unroll
      for (int nt = 0; nt < 4; ++nt) {
        int row = nt * 16 + l15;
        short8 kf = *(const short8*)((const char*)Kt +
            ((row * 512 + (kk * 32 + hi * 8) * 2) ^ ((row & 7) << 4)));
        s[nt] = __builtin_amdgcn_mfma_f32_16x16x32_bf16(qf[kk], kf, s[nt], 0, 0, 0);
      }
    }

    // scale, LeakyReLU, mask
    float pv[4][4];
#pragma unroll
    for (int nt = 0; nt < 4; ++nt) {
      int col = t * 64 + nt * 16 + l15;
#pragma unroll
      for (int r = 0; r < 4; ++r) {
        float v = s[nt][r] * 0.0625f;
        v = (v >= 0.f) ? v : 0.2f * v;
        int g = graph[(b * 1024 + qrow_c + r) * 1024 + col];
        pv[nt][r] = g ? v : -1e9f;
      }
    }

    // online softmax (wave-parallel: 16-lane group per row set)
#pragma unroll
    for (int r = 0; r < 4; ++r) {
      float rm = fmaxf(fmaxf(pv[0][r], pv[1][r]), fmaxf(pv[2][r], pv[3][r]));
      rm = fmaxf(rm, __shfl_xor(rm, 1));
      rm = fmaxf(rm, __shfl_xor(rm, 2));
      rm = fmaxf(rm, __shfl_xor(rm, 4));
      rm = fmaxf(rm, __shfl_xor(rm, 8));
      float mn = fmaxf(mR[r], rm);
      float corr = __expf(mR[r] - mn);
      mR[r] = mn;
      float rs = 0.f;
#pragma unroll
      for (int nt = 0; nt < 4; ++nt) {
        float p = __expf(pv[nt][r] - mn);
        pv[nt][r] = p;
        rs += p;
      }
      rs += __shfl_xor(rs, 1);
      rs += __shfl_xor(rs, 2);
      rs += __shfl_xor(rs, 4);
      rs += __shfl_xor(rs, 8);
      lR[r] = lR[r] * corr + rs;
#pragma unroll
      for (int dt = 0; dt < 16; ++dt) o[dt][r] *= corr;
    }

    // P (C-layout) -> per-wave LDS -> A-frag layout
    ushort* Pw = Pl + w * 1024;
#pragma unroll
    for (int nt = 0; nt < 4; ++nt)
#pragma unroll
      for (int r = 0; r < 4; ++r) {
        int row = hi * 4 + r, col = nt * 16 + l15;
        *(ushort*)((char*)Pw + ((row * 128 + col * 2) ^ ((row & 7) << 4))) =
            f2b(pv[nt][r]);
      }
    __asm__ volatile("s_waitcnt lgkmcnt(0)" ::: "memory");
    short8 pa[2];
#pragma unroll
    for (int ks = 0; ks < 2; ++ks)
      pa[ks] = *(const short8*)((const char*)Pw +
          ((l15 * 128 + (ks * 32 + hi * 8) * 2) ^ ((l15 & 7) << 4)));

    // O += P @ H
#pragma unroll
    for (int dt = 0; dt < 16; ++dt) {
#pragma unroll
      for (int ks = 0; ks < 2; ++ks) {
        int dcol = dt * 16 + l15;
        short8 hf = *(const short8*)((const char*)Ht +
            ((dcol * 128 + (ks * 32 + hi * 8) * 2) ^ ((dcol & 7) << 4)));
        o[dt] = __builtin_amdgcn_mfma_f32_16x16x32_bf16(pa[ks], hf, o[dt], 0, 0, 0);
      }
    }
  }

  // epilogue: normalize, relu, write fp32
#pragma unroll
  for (int r = 0; r < 4; ++r) {
    float inv = 1.f / lR[r];
#pragma unroll
    for (int dt = 0; dt < 16; ++dt) {
      float v = o[dt][r] * inv;
      out[(b * 1024 + qrow_c + r) * 256 + dt * 16 + l15] = fmaxf(v, 0.f);
    }
  }
}

extern "C" void kernel_launch(void* const* d_in, const int* in_sizes, int n_in,
                              void* d_out, int out_size, void* d_ws,
                              size_t ws_size, hipStream_t stream) {
  const float* feature = (const float*)d_in[0];
  const int* graph = (const int*)d_in[1];
  const float* W_w = (const float*)d_in[2];
  const float* W_b = (const float*)d_in[3];
  const float* Q_w = (const float*)d_in[4];
  const float* Q_b = (const float*)d_in[5];
  const float* K_w = (const float*)d_in[6];
  const float* K_b = (const float*)d_in[7];
  float* out = (float*)d_out;

  ushort* h = (ushort*)d_ws;          // [B,N,D] bf16   8 MB
  ushort* hT = h + MTOT * DD;         // [B,D,N] bf16   8 MB
  ushort* q = hT + MTOT * DD;         // [B,N,D] bf16   8 MB
  ushort* k = q + MTOT * DD;          // [B,N,D] bf16   8 MB

  dim3 blk(256);
  gemm_hqk<true, true><<<256, blk, 0, stream>>>(feature, W_w, W_b, h, hT);
  gemm_hqk<false, false><<<256, blk, 0, stream>>>(h, Q_w, Q_b, q, nullptr);
  gemm_hqk<false, false><<<256, blk, 0, stream>>>(h, K_w, K_b, k, nullptr);
  attn<<<256, blk, 0, stream>>>(q, k, hT, graph, out);
}